// Round 1
// baseline (356.474 us; speedup 1.0000x reference)
//
#include <hip/hip_runtime.h>
#include <hip/hip_bf16.h>

#define SEQ   128
#define BATCH 64
#define EMB   128
#define CELL  128
#define VOCAB 10000
#define NPADV 10240          // vocab rows padded to /64
#define ROWS  8192           // SEQ*BATCH
#define GATES 512            // 4*CELL
#define INDIM 256            // EMB+CELL (gate weight row stride)

typedef short  short8 __attribute__((ext_vector_type(8)));
typedef float  f32x4  __attribute__((ext_vector_type(4)));
typedef unsigned short u16;

static __device__ __forceinline__ u16 f2bf(float f) {
  union { float f; unsigned int u; } v; v.f = f;
  unsigned int u = v.u;
  return (u16)((u + 0x7fffu + ((u >> 16) & 1u)) >> 16);   // RNE
}
static __device__ __forceinline__ float fexp(float x) {
  return __builtin_amdgcn_exp2f(x * 1.44269504088896340736f);
}
static __device__ __forceinline__ float fsig(float x) {
  return __builtin_amdgcn_rcpf(1.0f + fexp(-x));
}
static __device__ __forceinline__ float ftanh(float x) {
  float e = fexp(2.0f * x);                 // e^(2x); overflows to inf -> returns 1 (ok)
  return 1.0f - 2.0f * __builtin_amdgcn_rcpf(e + 1.0f);
}

// ---------- prep kernels ----------
__global__ void k_convert_W(const float* __restrict__ W, u16* __restrict__ Wbf) {
  int idx = blockIdx.x * blockDim.x + threadIdx.x;
  if (idx >= NPADV * EMB) return;
  int v = idx >> 7, k = idx & 127;
  float val = (v < VOCAB) ? W[(size_t)v * EMB + k] : 0.f;
  Wbf[idx] = f2bf(val);
}

__global__ void k_build_gates(const float* __restrict__ Wc, const float* __restrict__ Bc,
                              const float* __restrict__ Wf, const float* __restrict__ Bf,
                              const float* __restrict__ Wi, const float* __restrict__ Bi,
                              const float* __restrict__ Wo, const float* __restrict__ Bo,
                              u16* __restrict__ Wall, float* __restrict__ Ball) {
  int idx = blockIdx.x * blockDim.x + threadIdx.x;
  if (idx < GATES * EMB) {
    int r = idx >> 7, k = idx & 127;
    int g = r >> 7, j = r & 127;
    const float* Wg = (g == 0) ? Wc : (g == 1) ? Wf : (g == 2) ? Wi : Wo;
    Wall[idx] = f2bf(Wg[(size_t)j * INDIM + k]);          // embedding-part columns 0..127
  }
  if (idx < GATES) {
    int g = idx >> 7, j = idx & 127;
    const float* Bg = (g == 0) ? Bc : (g == 1) ? Bf : (g == 2) ? Bi : Bo;
    Ball[idx] = Bg[j];
  }
}

__global__ void k_gather_xe(const int* __restrict__ x, const float* __restrict__ emb,
                            u16* __restrict__ Xe) {
  int idx = blockIdx.x * blockDim.x + threadIdx.x;
  if (idx >= ROWS * EMB) return;
  int c = idx >> 7, e = idx & 127;
  int tok = x[c];                                         // x is [SEQ][BATCH], c = t*64+b
  Xe[idx] = f2bf(emb[(size_t)tok * EMB + e]);
}

// ---------- bf16 MFMA GEMM: out[row][col] = sum_k A[row][k]*B[col][k] + bias[col] ----------
// A: [M][128] bf16 row-major, B: [Npad][128] bf16 row-major (B^T input), K=128 fixed.
// block = 256 thr (4 waves); block tile 64 rows x 64 cols; wave tile 64x16.
__launch_bounds__(256)
__global__ void k_gemm(const u16* __restrict__ A, const u16* __restrict__ B,
                       const float* __restrict__ bias, float* __restrict__ out,
                       int Nout) {
  int lane = threadIdx.x & 63;
  int wave = threadIdx.x >> 6;
  int lr = lane & 15;           // row (A) / col (B) within fragment
  int kh = lane >> 4;           // k-half-group: k = kh*8 + j
  int rowbase = blockIdx.y * 64;
  int colbase = blockIdx.x * 64 + wave * 16;
  int col = colbase + lr;

  const short8* A8 = (const short8*)A;
  const short8* B8 = (const short8*)B;

  f32x4 acc[4] = {};
#pragma unroll
  for (int ks = 0; ks < 4; ++ks) {
    short8 bfrag = B8[(size_t)(colbase + lr) * 16 + ks * 4 + kh];
#pragma unroll
    for (int m = 0; m < 4; ++m) {
      short8 afrag = A8[(size_t)(rowbase + m * 16 + lr) * 16 + ks * 4 + kh];
      acc[m] = __builtin_amdgcn_mfma_f32_16x16x32_bf16(afrag, bfrag, acc[m], 0, 0, 0);
    }
  }

  if (col < Nout) {
    float bv = bias ? bias[col] : 0.f;
#pragma unroll
    for (int m = 0; m < 4; ++m) {
#pragma unroll
      for (int q = 0; q < 4; ++q) {
        int row = rowbase + m * 16 + kh * 4 + q;          // C/D: col=lane&15, row=(lane>>4)*4+q
        out[(size_t)row * Nout + col] = acc[m][q] + bv;
      }
    }
  }
}

// ---------- sequential LSTM recurrence: one workgroup per batch column ----------
// 512 threads; thread r owns gate row r (g=r>>7: 0=c,1=f,2=i,3=o; j=r&127).
// Wh row (128 f32) lives in VGPRs; H broadcast via v_readlane from lane-resident regs.
__launch_bounds__(512, 2)
__global__ void k_recur(const float* __restrict__ Wc, const float* __restrict__ Wf,
                        const float* __restrict__ Wi, const float* __restrict__ Wo,
                        const float* __restrict__ Zin, u16* __restrict__ Hbf,
                        float* __restrict__ outHC) {
  __shared__ float Hl[CELL];
  __shared__ float zl[GATES];
  int tid = threadIdx.x;
  int b = blockIdx.x;
  int lane = tid & 63;
  int g = tid >> 7, j = tid & 127;
  const float* Wg = (g == 0) ? Wc : (g == 1) ? Wf : (g == 2) ? Wi : Wo;
  const float* wp = Wg + (size_t)j * INDIM + EMB;         // H-part columns 128..255

  float w[128];
#pragma unroll
  for (int k = 0; k < 128; ++k) w[k] = wp[k];

  if (tid < CELL) Hl[tid] = 0.f;
  float C = 0.f;
  __syncthreads();

  for (int t = 0; t < SEQ; ++t) {
    int c = t * BATCH + b;
    float zv = Zin[(size_t)c * GATES + tid];              // input-side preact + bias
    float h0 = Hl[lane];
    float h1 = Hl[lane + 64];
    float a0 = 0.f, a1 = 0.f, a2 = 0.f, a3 = 0.f;
#pragma unroll
    for (int k = 0; k < 32; ++k) {
      float p0 = __uint_as_float(__builtin_amdgcn_readlane(__float_as_uint(h0), k));
      a0 += w[k] * p0;
      float p1 = __uint_as_float(__builtin_amdgcn_readlane(__float_as_uint(h0), k + 32));
      a1 += w[k + 32] * p1;
      float p2 = __uint_as_float(__builtin_amdgcn_readlane(__float_as_uint(h1), k));
      a2 += w[k + 64] * p2;
      float p3 = __uint_as_float(__builtin_amdgcn_readlane(__float_as_uint(h1), k + 32));
      a3 += w[k + 96] * p3;
    }
    zl[tid] = zv + (a0 + a1) + (a2 + a3);
    __syncthreads();
    if (tid < CELL) {
      float cand = ftanh(zl[tid]);
      float F = fsig(zl[CELL + tid]);
      float I = fsig(zl[2 * CELL + tid]);
      float O = fsig(zl[3 * CELL + tid]);
      C = F * C + I * cand;
      float H = ftanh(C) * O;
      Hl[tid] = H;
      Hbf[(size_t)c * CELL + tid] = f2bf(H);
      if (t == SEQ - 1) {
        outHC[(size_t)tid * BATCH + b] = H;                       // Ht [128][64]
        outHC[(size_t)CELL * BATCH + (size_t)tid * BATCH + b] = C; // Ct [128][64]
      }
    }
    __syncthreads();
  }
}

extern "C" void kernel_launch(void* const* d_in, const int* in_sizes, int n_in,
                              void* d_out, int out_size, void* d_ws, size_t ws_size,
                              hipStream_t stream) {
  const int*   x   = (const int*)d_in[0];
  const float* emb = (const float*)d_in[1];
  const float* Wc  = (const float*)d_in[2];
  const float* Bc  = (const float*)d_in[3];
  const float* Wf  = (const float*)d_in[4];
  const float* Bf  = (const float*)d_in[5];
  const float* Wi  = (const float*)d_in[6];
  const float* Bi  = (const float*)d_in[7];
  const float* Wo  = (const float*)d_in[8];
  const float* Bo  = (const float*)d_in[9];
  const float* W   = (const float*)d_in[10];
  const float* b   = (const float*)d_in[11];
  float* out = (float*)d_out;

  char* ws = (char*)d_ws;
  size_t off = 0;
  auto alloc = [&](size_t bytes) -> void* {
    void* p = ws + off;
    off = (off + bytes + 255) & ~(size_t)255;
    return p;
  };
  u16*   Wbf  = (u16*)  alloc((size_t)NPADV * EMB * 2);   // 2.56 MB
  u16*   Wall = (u16*)  alloc((size_t)GATES * EMB * 2);   // 128 KB
  float* Ball = (float*)alloc((size_t)GATES * 4);         // 2 KB
  u16*   Xe   = (u16*)  alloc((size_t)ROWS * EMB * 2);    // 2 MB
  u16*   Hbf  = (u16*)  alloc((size_t)ROWS * CELL * 2);   // 2 MB
  float* Zin  = (float*)alloc((size_t)ROWS * GATES * 4);  // 16 MB

  hipLaunchKernelGGL(k_convert_W, dim3((NPADV * EMB + 255) / 256), dim3(256), 0, stream,
                     W, Wbf);
  hipLaunchKernelGGL(k_build_gates, dim3((GATES * EMB + 255) / 256), dim3(256), 0, stream,
                     Wc, Bc, Wf, Bf, Wi, Bi, Wo, Bo, Wall, Ball);
  hipLaunchKernelGGL(k_gather_xe, dim3((ROWS * EMB + 255) / 256), dim3(256), 0, stream,
                     x, emb, Xe);
  // Zin[c][r] = Xe[c]·Wall[r] + Ball[r]
  hipLaunchKernelGGL(k_gemm, dim3(GATES / 64, ROWS / 64), dim3(256), 0, stream,
                     Xe, Wall, Ball, Zin, GATES);
  // sequential recurrence, writes Hbf + final Ht/Ct
  hipLaunchKernelGGL(k_recur, dim3(BATCH), dim3(512), 0, stream,
                     Wc, Wf, Wi, Wo, Zin, Hbf, out + (size_t)ROWS * VOCAB);
  // out[c][v] = Hbf[c]·Wbf[v] + b[v]
  hipLaunchKernelGGL(k_gemm, dim3(NPADV / 64, ROWS / 64), dim3(256), 0, stream,
                     Hbf, Wbf, b, out, VOCAB);
}

// Round 2
// 354.657 us; speedup vs baseline: 1.0051x; 1.0051x over previous
//
#include <hip/hip_runtime.h>
#include <hip/hip_bf16.h>

#define SEQ   128
#define BATCH 64
#define EMB   128
#define CELL  128
#define VOCAB 10000
#define NPADV 10240          // vocab rows padded to /64
#define ROWS  8192           // SEQ*BATCH
#define GATES 512            // 4*CELL
#define INDIM 256            // EMB+CELL (gate weight row stride)

typedef short  short8 __attribute__((ext_vector_type(8)));
typedef float  f32x4  __attribute__((ext_vector_type(4)));
typedef unsigned short u16;

static __device__ __forceinline__ u16 f2bf(float f) {
  union { float f; unsigned int u; } v; v.f = f;
  unsigned int u = v.u;
  return (u16)((u + 0x7fffu + ((u >> 16) & 1u)) >> 16);   // RNE
}
static __device__ __forceinline__ float fexp(float x) {
  return __builtin_amdgcn_exp2f(x * 1.44269504088896340736f);
}
static __device__ __forceinline__ float fsig(float x) {
  return __builtin_amdgcn_rcpf(1.0f + fexp(-x));
}
static __device__ __forceinline__ float ftanh(float x) {
  float e = fexp(2.0f * x);                 // e^(2x); overflows to inf -> returns 1 (ok)
  return 1.0f - 2.0f * __builtin_amdgcn_rcpf(e + 1.0f);
}

// ---------- prep kernels ----------
__global__ void k_convert_W(const float* __restrict__ W, u16* __restrict__ Wbf) {
  int idx = blockIdx.x * blockDim.x + threadIdx.x;
  if (idx >= NPADV * EMB) return;
  int v = idx >> 7, k = idx & 127;
  float val = (v < VOCAB) ? W[(size_t)v * EMB + k] : 0.f;
  Wbf[idx] = f2bf(val);
}

__global__ void k_build_gates(const float* __restrict__ Wc, const float* __restrict__ Bc,
                              const float* __restrict__ Wf, const float* __restrict__ Bf,
                              const float* __restrict__ Wi, const float* __restrict__ Bi,
                              const float* __restrict__ Wo, const float* __restrict__ Bo,
                              u16* __restrict__ Wall, float* __restrict__ Ball) {
  int idx = blockIdx.x * blockDim.x + threadIdx.x;
  if (idx < GATES * EMB) {
    int r = idx >> 7, k = idx & 127;
    int g = r >> 7, j = r & 127;
    const float* Wg = (g == 0) ? Wc : (g == 1) ? Wf : (g == 2) ? Wi : Wo;
    Wall[idx] = f2bf(Wg[(size_t)j * INDIM + k]);          // embedding-part columns 0..127
  }
  if (idx < GATES) {
    int g = idx >> 7, j = idx & 127;
    const float* Bg = (g == 0) ? Bc : (g == 1) ? Bf : (g == 2) ? Bi : Bo;
    Ball[idx] = Bg[j];
  }
}

__global__ void k_gather_xe(const int* __restrict__ x, const float* __restrict__ emb,
                            u16* __restrict__ Xe) {
  int idx = blockIdx.x * blockDim.x + threadIdx.x;
  if (idx >= ROWS * EMB) return;
  int c = idx >> 7, e = idx & 127;
  int tok = x[c];                                         // x is [SEQ][BATCH], c = t*64+b
  Xe[idx] = f2bf(emb[(size_t)tok * EMB + e]);
}

// ---------- bf16 MFMA GEMM: out[row][col] = sum_k A[row][k]*B[col][k] + bias[col] ----------
// A: [M][128] bf16 row-major, B: [Npad][128] bf16 row-major (B^T input), K=128 fixed.
// block = 256 thr (4 waves); block tile 64 rows x 64 cols; wave computes 64r x 16c,
// then the tile is transposed through LDS so each wave stores 4 full 256B row
// segments per dwordx4 instruction (full 128B lines, 16 store instrs/block).
__launch_bounds__(256)
__global__ void k_gemm(const u16* __restrict__ A, const u16* __restrict__ B,
                       const float* __restrict__ bias, float* __restrict__ out,
                       int Nout) {
  __shared__ float tile[64][68];                // +4 pad: write conflicts 2-way, read 2-way
  int lane = threadIdx.x & 63;
  int wave = threadIdx.x >> 6;
  int lr = lane & 15;           // row (A) / col (B) within fragment
  int kh = lane >> 4;           // k-half-group: k = kh*8 + j
  int rowbase = blockIdx.y * 64;
  int colblk  = blockIdx.x * 64;
  int colbase = colblk + wave * 16;

  const short8* A8 = (const short8*)A;
  const short8* B8 = (const short8*)B;

  f32x4 acc[4] = {};
#pragma unroll
  for (int ks = 0; ks < 4; ++ks) {
    short8 bfrag = B8[(size_t)(colbase + lr) * 16 + ks * 4 + kh];
#pragma unroll
    for (int m = 0; m < 4; ++m) {
      short8 afrag = A8[(size_t)(rowbase + m * 16 + lr) * 16 + ks * 4 + kh];
      acc[m] = __builtin_amdgcn_mfma_f32_16x16x32_bf16(afrag, bfrag, acc[m], 0, 0, 0);
    }
  }

  // stage C/D fragments: lane holds col=colbase+lr, rows m*16+kh*4+q
#pragma unroll
  for (int m = 0; m < 4; ++m)
#pragma unroll
    for (int q = 0; q < 4; ++q)
      tile[m * 16 + kh * 4 + q][wave * 16 + lr] = acc[m][q];
  __syncthreads();

  // coalesced epilogue: wave w stores rows w*16..w*16+15; per instr 4 rows x 256B
  int col4 = lane & 15;
  int c = colblk + col4 * 4;
  if (c < Nout) {                               // Nout % 4 == 0, so no straddle
    f32x4 bv = {};
    if (bias) bv = *(const f32x4*)(bias + c);
#pragma unroll
    for (int i = 0; i < 4; ++i) {
      int r = wave * 16 + i * 4 + (lane >> 4);
      f32x4 v = *(const f32x4*)(&tile[r][col4 * 4]);
      v += bv;
      *(f32x4*)(out + (size_t)(rowbase + r) * Nout + c) = v;
    }
  }
}

// ---------- sequential LSTM recurrence: one workgroup per batch column ----------
// 512 threads; thread r owns gate row r (g=r>>7: 0=c,1=f,2=i,3=o; j=r&127).
// Wh row (128 f32) lives in VGPRs; H broadcast via v_readlane from lane-resident regs.
__launch_bounds__(512, 2)
__global__ void k_recur(const float* __restrict__ Wc, const float* __restrict__ Wf,
                        const float* __restrict__ Wi, const float* __restrict__ Wo,
                        const float* __restrict__ Zin, u16* __restrict__ Hbf,
                        float* __restrict__ outHC) {
  __shared__ float Hl[CELL];
  __shared__ float zl[GATES];
  int tid = threadIdx.x;
  int b = blockIdx.x;
  int lane = tid & 63;
  int g = tid >> 7, j = tid & 127;
  const float* Wg = (g == 0) ? Wc : (g == 1) ? Wf : (g == 2) ? Wi : Wo;
  const float* wp = Wg + (size_t)j * INDIM + EMB;         // H-part columns 128..255

  float w[128];
#pragma unroll
  for (int k = 0; k < 128; ++k) w[k] = wp[k];

  if (tid < CELL) Hl[tid] = 0.f;
  float C = 0.f;
  __syncthreads();

  for (int t = 0; t < SEQ; ++t) {
    int c = t * BATCH + b;
    float zv = Zin[(size_t)c * GATES + tid];              // input-side preact + bias
    float h0 = Hl[lane];
    float h1 = Hl[lane + 64];
    float a0 = 0.f, a1 = 0.f, a2 = 0.f, a3 = 0.f;
#pragma unroll
    for (int k = 0; k < 32; ++k) {
      float p0 = __uint_as_float(__builtin_amdgcn_readlane(__float_as_uint(h0), k));
      a0 += w[k] * p0;
      float p1 = __uint_as_float(__builtin_amdgcn_readlane(__float_as_uint(h0), k + 32));
      a1 += w[k + 32] * p1;
      float p2 = __uint_as_float(__builtin_amdgcn_readlane(__float_as_uint(h1), k));
      a2 += w[k + 64] * p2;
      float p3 = __uint_as_float(__builtin_amdgcn_readlane(__float_as_uint(h1), k + 32));
      a3 += w[k + 96] * p3;
    }
    zl[tid] = zv + (a0 + a1) + (a2 + a3);
    __syncthreads();
    if (tid < CELL) {
      float cand = ftanh(zl[tid]);
      float F = fsig(zl[CELL + tid]);
      float I = fsig(zl[2 * CELL + tid]);
      float O = fsig(zl[3 * CELL + tid]);
      C = F * C + I * cand;
      float H = ftanh(C) * O;
      Hl[tid] = H;
      Hbf[(size_t)c * CELL + tid] = f2bf(H);
      if (t == SEQ - 1) {
        outHC[(size_t)tid * BATCH + b] = H;                       // Ht [128][64]
        outHC[(size_t)CELL * BATCH + (size_t)tid * BATCH + b] = C; // Ct [128][64]
      }
    }
    __syncthreads();
  }
}

extern "C" void kernel_launch(void* const* d_in, const int* in_sizes, int n_in,
                              void* d_out, int out_size, void* d_ws, size_t ws_size,
                              hipStream_t stream) {
  const int*   x   = (const int*)d_in[0];
  const float* emb = (const float*)d_in[1];
  const float* Wc  = (const float*)d_in[2];
  const float* Bc  = (const float*)d_in[3];
  const float* Wf  = (const float*)d_in[4];
  const float* Bf  = (const float*)d_in[5];
  const float* Wi  = (const float*)d_in[6];
  const float* Bi  = (const float*)d_in[7];
  const float* Wo  = (const float*)d_in[8];
  const float* Bo  = (const float*)d_in[9];
  const float* W   = (const float*)d_in[10];
  const float* b   = (const float*)d_in[11];
  float* out = (float*)d_out;

  char* ws = (char*)d_ws;
  size_t off = 0;
  auto alloc = [&](size_t bytes) -> void* {
    void* p = ws + off;
    off = (off + bytes + 255) & ~(size_t)255;
    return p;
  };
  u16*   Wbf  = (u16*)  alloc((size_t)NPADV * EMB * 2);   // 2.56 MB
  u16*   Wall = (u16*)  alloc((size_t)GATES * EMB * 2);   // 128 KB
  float* Ball = (float*)alloc((size_t)GATES * 4);         // 2 KB
  u16*   Xe   = (u16*)  alloc((size_t)ROWS * EMB * 2);    // 2 MB
  u16*   Hbf  = (u16*)  alloc((size_t)ROWS * CELL * 2);   // 2 MB
  float* Zin  = (float*)alloc((size_t)ROWS * GATES * 4);  // 16 MB

  hipLaunchKernelGGL(k_convert_W, dim3((NPADV * EMB + 255) / 256), dim3(256), 0, stream,
                     W, Wbf);
  hipLaunchKernelGGL(k_build_gates, dim3((GATES * EMB + 255) / 256), dim3(256), 0, stream,
                     Wc, Bc, Wf, Bf, Wi, Bi, Wo, Bo, Wall, Ball);
  hipLaunchKernelGGL(k_gather_xe, dim3((ROWS * EMB + 255) / 256), dim3(256), 0, stream,
                     x, emb, Xe);
  // Zin[c][r] = Xe[c]·Wall[r] + Ball[r]
  hipLaunchKernelGGL(k_gemm, dim3(GATES / 64, ROWS / 64), dim3(256), 0, stream,
                     Xe, Wall, Ball, Zin, GATES);
  // sequential recurrence, writes Hbf + final Ht/Ct
  hipLaunchKernelGGL(k_recur, dim3(BATCH), dim3(512), 0, stream,
                     Wc, Wf, Wi, Wo, Zin, Hbf, out + (size_t)ROWS * VOCAB);
  // out[c][v] = Hbf[c]·Wbf[v] + b[v]
  hipLaunchKernelGGL(k_gemm, dim3(NPADV / 64, ROWS / 64), dim3(256), 0, stream,
                     Hbf, Wbf, b, out, VOCAB);
}

// Round 3
// 333.889 us; speedup vs baseline: 1.0676x; 1.0622x over previous
//
#include <hip/hip_runtime.h>
#include <hip/hip_bf16.h>

#define SEQ   128
#define BATCH 64
#define EMB   128
#define CELL  128
#define VOCAB 10000
#define NPADV 10240          // vocab rows padded to /64
#define ROWS  8192           // SEQ*BATCH
#define GATES 512            // 4*CELL
#define INDIM 256            // EMB+CELL (gate weight row stride)
#define VCHUNK 256           // vocab cols per chunk in k_vocab

typedef short  short8 __attribute__((ext_vector_type(8)));
typedef float  f32x4  __attribute__((ext_vector_type(4)));
typedef unsigned short u16;

static __device__ __forceinline__ u16 f2bf(float f) {
  union { float f; unsigned int u; } v; v.f = f;
  unsigned int u = v.u;
  return (u16)((u + 0x7fffu + ((u >> 16) & 1u)) >> 16);   // RNE
}
static __device__ __forceinline__ float fexp(float x) {
  return __builtin_amdgcn_exp2f(x * 1.44269504088896340736f);
}
static __device__ __forceinline__ float fsig(float x) {
  return __builtin_amdgcn_rcpf(1.0f + fexp(-x));
}
static __device__ __forceinline__ float ftanh(float x) {
  float e = fexp(2.0f * x);                 // e^(2x); overflows to inf -> returns 1 (ok)
  return 1.0f - 2.0f * __builtin_amdgcn_rcpf(e + 1.0f);
}

// ---------- prep kernels ----------
__global__ void k_convert_W(const float* __restrict__ W, u16* __restrict__ Wbf) {
  int idx = blockIdx.x * blockDim.x + threadIdx.x;
  if (idx >= NPADV * EMB) return;
  int v = idx >> 7, k = idx & 127;
  float val = (v < VOCAB) ? W[(size_t)v * EMB + k] : 0.f;
  Wbf[idx] = f2bf(val);
}

__global__ void k_build_gates(const float* __restrict__ Wc, const float* __restrict__ Bc,
                              const float* __restrict__ Wf, const float* __restrict__ Bf,
                              const float* __restrict__ Wi, const float* __restrict__ Bi,
                              const float* __restrict__ Wo, const float* __restrict__ Bo,
                              u16* __restrict__ Wall, float* __restrict__ Ball) {
  int idx = blockIdx.x * blockDim.x + threadIdx.x;
  if (idx < GATES * EMB) {
    int r = idx >> 7, k = idx & 127;
    int g = r >> 7, j = r & 127;
    const float* Wg = (g == 0) ? Wc : (g == 1) ? Wf : (g == 2) ? Wi : Wo;
    Wall[idx] = f2bf(Wg[(size_t)j * INDIM + k]);          // embedding-part columns 0..127
  }
  if (idx < GATES) {
    int g = idx >> 7, j = idx & 127;
    const float* Bg = (g == 0) ? Bc : (g == 1) ? Bf : (g == 2) ? Bi : Bo;
    Ball[idx] = Bg[j];
  }
}

__global__ void k_gather_xe(const int* __restrict__ x, const float* __restrict__ emb,
                            u16* __restrict__ Xe) {
  int idx = blockIdx.x * blockDim.x + threadIdx.x;
  if (idx >= ROWS * EMB) return;
  int c = idx >> 7, e = idx & 127;
  int tok = x[c];                                         // x is [SEQ][BATCH], c = t*64+b
  Xe[idx] = f2bf(emb[(size_t)tok * EMB + e]);
}

// ---------- small bf16 MFMA GEMM (Zin): out[row][col] = A[row]·B[col] + bias[col] ----------
__launch_bounds__(256)
__global__ void k_gemm(const u16* __restrict__ A, const u16* __restrict__ B,
                       const float* __restrict__ bias, float* __restrict__ out,
                       int Nout) {
  __shared__ float tile[64][68];
  int lane = threadIdx.x & 63;
  int wave = threadIdx.x >> 6;
  int lr = lane & 15;
  int kh = lane >> 4;
  int rowbase = blockIdx.y * 64;
  int colblk  = blockIdx.x * 64;
  int colbase = colblk + wave * 16;

  const short8* A8 = (const short8*)A;
  const short8* B8 = (const short8*)B;

  f32x4 acc[4] = {};
#pragma unroll
  for (int ks = 0; ks < 4; ++ks) {
    short8 bfrag = B8[(size_t)(colbase + lr) * 16 + ks * 4 + kh];
#pragma unroll
    for (int m = 0; m < 4; ++m) {
      short8 afrag = A8[(size_t)(rowbase + m * 16 + lr) * 16 + ks * 4 + kh];
      acc[m] = __builtin_amdgcn_mfma_f32_16x16x32_bf16(afrag, bfrag, acc[m], 0, 0, 0);
    }
  }

#pragma unroll
  for (int m = 0; m < 4; ++m)
#pragma unroll
    for (int q = 0; q < 4; ++q)
      tile[m * 16 + kh * 4 + q][wave * 16 + lr] = acc[m][q];
  __syncthreads();

  int col4 = lane & 15;
  int c = colblk + col4 * 4;
  if (c < Nout) {
    f32x4 bv = {};
    if (bias) bv = *(const f32x4*)(bias + c);
#pragma unroll
    for (int i = 0; i < 4; ++i) {
      int r = wave * 16 + i * 4 + (lane >> 4);
      f32x4 v = *(const f32x4*)(&tile[r][col4 * 4]);
      v += bv;
      *(f32x4*)(out + (size_t)(rowbase + r) * Nout + c) = v;
    }
  }
}

// ---------- vocab projection: one block owns 16 COMPLETE output rows ----------
// Each block streams 16 x 40000B fully contiguous row ranges -> no cache line is
// shared between blocks (output row stride 40000B is not 128B-aligned, so any
// column tiling creates cross-XCD partial-line writes; row ownership avoids it).
// A-frags (16 rows x K=128) live in VGPRs; B (2.56MB) is L2-resident.
__launch_bounds__(256, 2)
__global__ void k_vocab(const u16* __restrict__ A, const u16* __restrict__ B,
                        const float* __restrict__ bias, float* __restrict__ out) {
  __shared__ float lds[2][16][VCHUNK + 4];
  int tid = threadIdx.x;
  int lane = tid & 63, wave = tid >> 6;
  int lr = lane & 15, kh = lane >> 4;
  int rowbase = blockIdx.x * 16;

  const short8* A8 = (const short8*)A;
  const short8* B8 = (const short8*)B;

  short8 af[4];
#pragma unroll
  for (int ks = 0; ks < 4; ++ks)
    af[ks] = A8[(size_t)(rowbase + lr) * 16 + ks * 4 + kh];

  for (int cb = 0; cb < NPADV / VCHUNK; ++cb) {
    int buf = cb & 1;
    int chunkbase = cb * VCHUNK;

    f32x4 acc[4] = {{}, {}, {}, {}};
#pragma unroll
    for (int cf = 0; cf < 4; ++cf) {
      int colbase = chunkbase + wave * 64 + cf * 16;
#pragma unroll
      for (int ks = 0; ks < 4; ++ks) {
        short8 bf = B8[(size_t)(colbase + lr) * 16 + ks * 4 + kh];
        acc[cf] = __builtin_amdgcn_mfma_f32_16x16x32_bf16(af[ks], bf, acc[cf], 0, 0, 0);
      }
    }

    // C/D: col = colbase+lr, row = kh*4+q (rows 0..15 of the band)
#pragma unroll
    for (int cf = 0; cf < 4; ++cf)
#pragma unroll
      for (int q = 0; q < 4; ++q)
        lds[buf][kh * 4 + q][wave * 64 + cf * 16 + lr] = acc[cf][q];
    __syncthreads();

    // store: 4 iters, each = 4 rows x 1KB contiguous (64 lanes x dwordx4)
#pragma unroll
    for (int i = 0; i < 4; ++i) {
      int r = wave + i * 4;
      int col = chunkbase + (tid & 63) * 4;
      if (col < VOCAB) {
        f32x4 v = *(const f32x4*)(&lds[buf][r][(tid & 63) * 4]);
        v += *(const f32x4*)(bias + col);
        *(f32x4*)(out + (size_t)(rowbase + r) * VOCAB + col) = v;
      }
    }
    // ping-pong LDS: next chunk writes buf^1, which was read a full barrier ago
  }
}

// ---------- sequential LSTM recurrence: one workgroup per batch column ----------
__launch_bounds__(512, 2)
__global__ void k_recur(const float* __restrict__ Wc, const float* __restrict__ Wf,
                        const float* __restrict__ Wi, const float* __restrict__ Wo,
                        const float* __restrict__ Zin, u16* __restrict__ Hbf,
                        float* __restrict__ outHC) {
  __shared__ float Hl[CELL];
  __shared__ float zl[GATES];
  int tid = threadIdx.x;
  int b = blockIdx.x;
  int lane = tid & 63;
  int g = tid >> 7, j = tid & 127;
  const float* Wg = (g == 0) ? Wc : (g == 1) ? Wf : (g == 2) ? Wi : Wo;
  const float* wp = Wg + (size_t)j * INDIM + EMB;

  float w[128];
#pragma unroll
  for (int k = 0; k < 128; ++k) w[k] = wp[k];

  if (tid < CELL) Hl[tid] = 0.f;
  float C = 0.f;
  __syncthreads();

  for (int t = 0; t < SEQ; ++t) {
    int c = t * BATCH + b;
    float zv = Zin[(size_t)c * GATES + tid];
    float h0 = Hl[lane];
    float h1 = Hl[lane + 64];
    float a0 = 0.f, a1 = 0.f, a2 = 0.f, a3 = 0.f;
#pragma unroll
    for (int k = 0; k < 32; ++k) {
      float p0 = __uint_as_float(__builtin_amdgcn_readlane(__float_as_uint(h0), k));
      a0 += w[k] * p0;
      float p1 = __uint_as_float(__builtin_amdgcn_readlane(__float_as_uint(h0), k + 32));
      a1 += w[k + 32] * p1;
      float p2 = __uint_as_float(__builtin_amdgcn_readlane(__float_as_uint(h1), k));
      a2 += w[k + 64] * p2;
      float p3 = __uint_as_float(__builtin_amdgcn_readlane(__float_as_uint(h1), k + 32));
      a3 += w[k + 96] * p3;
    }
    zl[tid] = zv + (a0 + a1) + (a2 + a3);
    __syncthreads();
    if (tid < CELL) {
      float cand = ftanh(zl[tid]);
      float F = fsig(zl[CELL + tid]);
      float I = fsig(zl[2 * CELL + tid]);
      float O = fsig(zl[3 * CELL + tid]);
      C = F * C + I * cand;
      float H = ftanh(C) * O;
      Hl[tid] = H;
      Hbf[(size_t)c * CELL + tid] = f2bf(H);
      if (t == SEQ - 1) {
        outHC[(size_t)tid * BATCH + b] = H;
        outHC[(size_t)CELL * BATCH + (size_t)tid * BATCH + b] = C;
      }
    }
    __syncthreads();
  }
}

extern "C" void kernel_launch(void* const* d_in, const int* in_sizes, int n_in,
                              void* d_out, int out_size, void* d_ws, size_t ws_size,
                              hipStream_t stream) {
  const int*   x   = (const int*)d_in[0];
  const float* emb = (const float*)d_in[1];
  const float* Wc  = (const float*)d_in[2];
  const float* Bc  = (const float*)d_in[3];
  const float* Wf  = (const float*)d_in[4];
  const float* Bf  = (const float*)d_in[5];
  const float* Wi  = (const float*)d_in[6];
  const float* Bi  = (const float*)d_in[7];
  const float* Wo  = (const float*)d_in[8];
  const float* Bo  = (const float*)d_in[9];
  const float* W   = (const float*)d_in[10];
  const float* b   = (const float*)d_in[11];
  float* out = (float*)d_out;

  char* ws = (char*)d_ws;
  size_t off = 0;
  auto alloc = [&](size_t bytes) -> void* {
    void* p = ws + off;
    off = (off + bytes + 255) & ~(size_t)255;
    return p;
  };
  u16*   Wbf  = (u16*)  alloc((size_t)NPADV * EMB * 2);   // 2.56 MB
  u16*   Wall = (u16*)  alloc((size_t)GATES * EMB * 2);   // 128 KB
  float* Ball = (float*)alloc((size_t)GATES * 4);         // 2 KB
  u16*   Xe   = (u16*)  alloc((size_t)ROWS * EMB * 2);    // 2 MB
  u16*   Hbf  = (u16*)  alloc((size_t)ROWS * CELL * 2);   // 2 MB
  float* Zin  = (float*)alloc((size_t)ROWS * GATES * 4);  // 16 MB

  hipLaunchKernelGGL(k_convert_W, dim3((NPADV * EMB + 255) / 256), dim3(256), 0, stream,
                     W, Wbf);
  hipLaunchKernelGGL(k_build_gates, dim3((GATES * EMB + 255) / 256), dim3(256), 0, stream,
                     Wc, Bc, Wf, Bf, Wi, Bi, Wo, Bo, Wall, Ball);
  hipLaunchKernelGGL(k_gather_xe, dim3((ROWS * EMB + 255) / 256), dim3(256), 0, stream,
                     x, emb, Xe);
  // Zin[c][r] = Xe[c]·Wall[r] + Ball[r]
  hipLaunchKernelGGL(k_gemm, dim3(GATES / 64, ROWS / 64), dim3(256), 0, stream,
                     Xe, Wall, Ball, Zin, GATES);
  // sequential recurrence, writes Hbf + final Ht/Ct
  hipLaunchKernelGGL(k_recur, dim3(BATCH), dim3(512), 0, stream,
                     Wc, Wf, Wi, Wo, Zin, Hbf, out + (size_t)ROWS * VOCAB);
  // out[c][v] = Hbf[c]·Wbf[v] + b[v]  (row-band blocks, contiguous row writes)
  hipLaunchKernelGGL(k_vocab, dim3(ROWS / 16), dim3(256), 0, stream,
                     Hbf, Wbf, b, out);
}